// Round 15
// baseline (228.117 us; speedup 1.0000x reference)
//
#include <hip/hip_runtime.h>
#include <hip/hip_bf16.h>

#define N_NODES 50000
#define N_EDGES 800000
#define DIM 128
#define N_GR 500
#define N_OUT 10

typedef unsigned short u16;
typedef unsigned int u32;
typedef __attribute__((ext_vector_type(8))) short bf16x8;
typedef __attribute__((ext_vector_type(4))) float f32x4;

#define MFMA16(a, b, c) __builtin_amdgcn_mfma_f32_16x16x32_bf16(a, b, c, 0, 0, 0)

__device__ __forceinline__ float bf2f(u16 u) {
    union { u32 i; float f; } c; c.i = ((u32)u) << 16; return c.f;
}
__device__ __forceinline__ u16 f2bf(float f) {
    union { float f; u32 i; } c; c.f = f;
    u32 i = c.i;
    u32 r = i + 0x7FFFu + ((i >> 16) & 1u);
    return (u16)(r >> 16);
}
__device__ __forceinline__ u32 pack2(float a, float b) {
    return (u32)f2bf(a) | ((u32)f2bf(b) << 16);
}

#define GB_HIST 3125                                   // 800000/256
#define GB_GATH 6250                                   // 50000*32/256
#define NSCANB 196                                     // ceil(50000/256)

// ---- combined: hist (deg+rank) blocks [0,3125) | gather blocks [3125,9375) ----
__global__ __launch_bounds__(256) void k_hist_gather(const int* __restrict__ dst,
                                                     int* __restrict__ deg,
                                                     u16* __restrict__ rank16,
                                                     const int* __restrict__ ids,
                                                     const float* __restrict__ emb,
                                                     float* __restrict__ xout) {
    int b = blockIdx.x;
    if (b < GB_HIST) {
        int e = b * 256 + threadIdx.x;
        if (e >= N_EDGES) return;
        int r = atomicAdd(&deg[dst[e]], 1);
        rank16[e] = (u16)r;
    } else {
        int gid = (b - GB_HIST) * 256 + threadIdx.x;   // N*32 threads
        int node = gid >> 5, seg = gid & 31;
        int id = ids[node];
        f32x4 v = *(const f32x4*)(emb + id * DIM + seg * 4);
        __builtin_nontemporal_store(v, (f32x4*)(xout + node * DIM + seg * 4));
    }
}

// ---- single-kernel exclusive scan via decoupled lookback (196 blocks, all resident) ----
__global__ __launch_bounds__(256) void k_scan(const int* __restrict__ deg,
                                              int* __restrict__ rowptr,
                                              u32* __restrict__ stat) {
    __shared__ int s[256];
    __shared__ int exc_s;
    int t = threadIdx.x, b = blockIdx.x;
    int idx = b * 256 + t;
    int v = (idx < N_NODES) ? deg[idx] : 0;
    s[t] = v; __syncthreads();
    for (int o = 1; o < 256; o <<= 1) {
        int x = (t >= o) ? s[t - o] : 0;
        __syncthreads();
        s[t] += x;
        __syncthreads();
    }
    int aggr = s[255];
    if (t == 0) {
        if (b == 0) {
            __hip_atomic_store(&stat[0], (2u << 30) | (u32)aggr, __ATOMIC_RELEASE, __HIP_MEMORY_SCOPE_AGENT);
            exc_s = 0;
        } else {
            __hip_atomic_store(&stat[b], (1u << 30) | (u32)aggr, __ATOMIC_RELEASE, __HIP_MEMORY_SCOPE_AGENT);
            int sum = 0;
            for (int j = b - 1; j >= 0; j--) {
                u32 sv;
                do {
                    sv = __hip_atomic_load(&stat[j], __ATOMIC_ACQUIRE, __HIP_MEMORY_SCOPE_AGENT);
                } while ((sv >> 30) == 0u);
                sum += (int)(sv & 0x3FFFFFFFu);
                if ((sv >> 30) == 2u) break;            // inclusive prefix found
            }
            __hip_atomic_store(&stat[b], (2u << 30) | (u32)(sum + aggr), __ATOMIC_RELEASE, __HIP_MEMORY_SCOPE_AGENT);
            exc_s = sum;
        }
    }
    __syncthreads();
    int ex = exc_s + s[t] - v;                          // exclusive prefix for idx
    if (idx < N_NODES) rowptr[idx] = ex;
    if (idx == N_NODES - 1) rowptr[N_NODES] = ex + v;
}

// ---- fill (atomic-free): sid[rowptr[dst]+rank] = src | (x_ids[src] << 17) ----
__global__ __launch_bounds__(256) void k_fill(const int* __restrict__ src,
                                              const int* __restrict__ dst,
                                              const int* __restrict__ xids,
                                              const int* __restrict__ rowptr,
                                              const u16* __restrict__ rank16,
                                              u32* __restrict__ sid) {
    int e = blockIdx.x * 256 + threadIdx.x;
    if (e >= N_EDGES) return;
    int s = src[e];
    int pos = rowptr[dst[e]] + rank16[e];
    sid[pos] = (u32)s | ((u32)xids[s] << 17);
}

// ---- prep: weights -> wT bf16 swizzled + emb bf16 table + zero deg + zero stat ----
__global__ __launch_bounds__(256) void k_prep(const float* __restrict__ w11, const float* __restrict__ w12,
                                              const float* __restrict__ w21, const float* __restrict__ w22,
                                              const float* __restrict__ emb,
                                              u16* __restrict__ wout, u16* __restrict__ embbf,
                                              int* __restrict__ deg, u32* __restrict__ stat) {
    int g = blockIdx.x * 256 + threadIdx.x;
    if (g < 4 * 8192) {
        int mat = g >> 13, r = g & 8191;
        int j = r & 127, k0 = (r >> 7) * 2;
        const float* w = (mat == 0) ? w11 : (mat == 1) ? w12 : (mat == 2) ? w21 : w22;
        float v0 = w[k0 * DIM + j];
        float v1 = w[(k0 + 1) * DIM + j];
        char* base = (char*)(wout + mat * 16384);
        *(u32*)(base + j * 256 + ((2 * k0) ^ ((j & 7) << 4))) = pack2(v0, v1);
    } else if (g < 64768) {
        int i = g - 4 * 8192;                          // 0..31999
        float2 p = *(const float2*)(emb + i * 2);
        ((u32*)embbf)[i] = pack2(p.x, p.y);
    } else {
        int i = g - 64768;
        if (i < N_NODES) deg[i] = 0;
        if (i < NSCANB) stat[i] = 0;
    }
}

// ---- layer-1 aggregate from 128 KB embbf table; 8-way ILP, bf16 out ---------
__global__ __launch_bounds__(256) void k_agg_emb(const u16* __restrict__ embbf,
                                                 const u32* __restrict__ sid,
                                                 const int* __restrict__ rowptr,
                                                 u16* __restrict__ aggbf) {
    int wave = (blockIdx.x * 256 + threadIdx.x) >> 6;
    if (wave >= N_NODES) return;
    int lane = threadIdx.x & 63;
    int beg = rowptr[wave], end = rowptr[wave + 1];
    float ax0 = 0.f, ay0 = 0.f, ax1 = 0.f, ay1 = 0.f;
    float ax2 = 0.f, ay2 = 0.f, ax3 = 0.f, ay3 = 0.f;
    int i = beg;
    for (; i + 8 <= end; i += 8) {
        int s0 = sid[i] >> 17,     s1 = sid[i + 1] >> 17;
        int s2 = sid[i + 2] >> 17, s3 = sid[i + 3] >> 17;
        int s4 = sid[i + 4] >> 17, s5 = sid[i + 5] >> 17;
        int s6 = sid[i + 6] >> 17, s7 = sid[i + 7] >> 17;
        u32 v0 = *(const u32*)(embbf + s0 * DIM + lane * 2);
        u32 v1 = *(const u32*)(embbf + s1 * DIM + lane * 2);
        u32 v2 = *(const u32*)(embbf + s2 * DIM + lane * 2);
        u32 v3 = *(const u32*)(embbf + s3 * DIM + lane * 2);
        u32 v4 = *(const u32*)(embbf + s4 * DIM + lane * 2);
        u32 v5 = *(const u32*)(embbf + s5 * DIM + lane * 2);
        u32 v6 = *(const u32*)(embbf + s6 * DIM + lane * 2);
        u32 v7 = *(const u32*)(embbf + s7 * DIM + lane * 2);
        ax0 += bf2f((u16)v0) + bf2f((u16)v4); ay0 += bf2f((u16)(v0 >> 16)) + bf2f((u16)(v4 >> 16));
        ax1 += bf2f((u16)v1) + bf2f((u16)v5); ay1 += bf2f((u16)(v1 >> 16)) + bf2f((u16)(v5 >> 16));
        ax2 += bf2f((u16)v2) + bf2f((u16)v6); ay2 += bf2f((u16)(v2 >> 16)) + bf2f((u16)(v6 >> 16));
        ax3 += bf2f((u16)v3) + bf2f((u16)v7); ay3 += bf2f((u16)(v3 >> 16)) + bf2f((u16)(v7 >> 16));
    }
    for (; i + 4 <= end; i += 4) {
        int s0 = sid[i] >> 17, s1 = sid[i + 1] >> 17, s2 = sid[i + 2] >> 17, s3 = sid[i + 3] >> 17;
        u32 v0 = *(const u32*)(embbf + s0 * DIM + lane * 2);
        u32 v1 = *(const u32*)(embbf + s1 * DIM + lane * 2);
        u32 v2 = *(const u32*)(embbf + s2 * DIM + lane * 2);
        u32 v3 = *(const u32*)(embbf + s3 * DIM + lane * 2);
        ax0 += bf2f((u16)v0); ay0 += bf2f((u16)(v0 >> 16));
        ax1 += bf2f((u16)v1); ay1 += bf2f((u16)(v1 >> 16));
        ax2 += bf2f((u16)v2); ay2 += bf2f((u16)(v2 >> 16));
        ax3 += bf2f((u16)v3); ay3 += bf2f((u16)(v3 >> 16));
    }
    for (; i < end; i++) {
        int s = sid[i] >> 17;
        u32 v = *(const u32*)(embbf + s * DIM + lane * 2);
        ax0 += bf2f((u16)v); ay0 += bf2f((u16)(v >> 16));
    }
    float ax = (ax0 + ax1) + (ax2 + ax3);
    float ay = (ay0 + ay1) + (ay2 + ay3);
    *(u32*)(aggbf + wave * DIM + lane * 2) = pack2(ax, ay);
}

// ---- layer-2 aggregate from h1; 8-way ILP, bf16 out -------------------------
__global__ __launch_bounds__(256) void k_agg_bf16(const u16* __restrict__ x,
                                                  const int* __restrict__ rowptr,
                                                  const u32* __restrict__ sid,
                                                  u16* __restrict__ aggbf) {
    int wave = (blockIdx.x * 256 + threadIdx.x) >> 6;
    if (wave >= N_NODES) return;
    int lane = threadIdx.x & 63;
    int beg = rowptr[wave], end = rowptr[wave + 1];
    float ax0 = 0.f, ay0 = 0.f, ax1 = 0.f, ay1 = 0.f;
    float ax2 = 0.f, ay2 = 0.f, ax3 = 0.f, ay3 = 0.f;
    int i = beg;
    for (; i + 8 <= end; i += 8) {
        int s0 = sid[i] & 0x1FFFF,     s1 = sid[i + 1] & 0x1FFFF;
        int s2 = sid[i + 2] & 0x1FFFF, s3 = sid[i + 3] & 0x1FFFF;
        int s4 = sid[i + 4] & 0x1FFFF, s5 = sid[i + 5] & 0x1FFFF;
        int s6 = sid[i + 6] & 0x1FFFF, s7 = sid[i + 7] & 0x1FFFF;
        u32 v0 = *(const u32*)(x + s0 * DIM + lane * 2);
        u32 v1 = *(const u32*)(x + s1 * DIM + lane * 2);
        u32 v2 = *(const u32*)(x + s2 * DIM + lane * 2);
        u32 v3 = *(const u32*)(x + s3 * DIM + lane * 2);
        u32 v4 = *(const u32*)(x + s4 * DIM + lane * 2);
        u32 v5 = *(const u32*)(x + s5 * DIM + lane * 2);
        u32 v6 = *(const u32*)(x + s6 * DIM + lane * 2);
        u32 v7 = *(const u32*)(x + s7 * DIM + lane * 2);
        ax0 += bf2f((u16)v0) + bf2f((u16)v4); ay0 += bf2f((u16)(v0 >> 16)) + bf2f((u16)(v4 >> 16));
        ax1 += bf2f((u16)v1) + bf2f((u16)v5); ay1 += bf2f((u16)(v1 >> 16)) + bf2f((u16)(v5 >> 16));
        ax2 += bf2f((u16)v2) + bf2f((u16)v6); ay2 += bf2f((u16)(v2 >> 16)) + bf2f((u16)(v6 >> 16));
        ax3 += bf2f((u16)v3) + bf2f((u16)v7); ay3 += bf2f((u16)(v3 >> 16)) + bf2f((u16)(v7 >> 16));
    }
    for (; i + 4 <= end; i += 4) {
        int s0 = sid[i] & 0x1FFFF, s1 = sid[i + 1] & 0x1FFFF;
        int s2 = sid[i + 2] & 0x1FFFF, s3 = sid[i + 3] & 0x1FFFF;
        u32 v0 = *(const u32*)(x + s0 * DIM + lane * 2);
        u32 v1 = *(const u32*)(x + s1 * DIM + lane * 2);
        u32 v2 = *(const u32*)(x + s2 * DIM + lane * 2);
        u32 v3 = *(const u32*)(x + s3 * DIM + lane * 2);
        ax0 += bf2f((u16)v0); ay0 += bf2f((u16)(v0 >> 16));
        ax1 += bf2f((u16)v1); ay1 += bf2f((u16)(v1 >> 16));
        ax2 += bf2f((u16)v2); ay2 += bf2f((u16)(v2 >> 16));
        ax3 += bf2f((u16)v3); ay3 += bf2f((u16)(v3 >> 16));
    }
    for (; i < end; i++) {
        int s = sid[i] & 0x1FFFF;
        u32 v = *(const u32*)(x + s * DIM + lane * 2);
        ax0 += bf2f((u16)v); ay0 += bf2f((u16)(v >> 16));
    }
    float ax = (ax0 + ax1) + (ax2 + ax3);
    float ay = (ay0 + ay1) + (ay2 + ay3);
    *(u32*)(aggbf + wave * DIM + lane * 2) = pack2(ax, ay);
}

// ------- fused GIN MLP via MFMA; B-fragments read DIRECTLY from L2-hot global -------
template<bool GATHER>
__global__ __launch_bounds__(256) void k_mlp(const u16* __restrict__ xin,
                                             const int* __restrict__ ids,
                                             const u16* __restrict__ aggbf,
                                             const u16* __restrict__ wsa, const float* __restrict__ ba,
                                             const float* __restrict__ gg, const float* __restrict__ be,
                                             const float* __restrict__ mm, const float* __restrict__ vv,
                                             const u16* __restrict__ wsb, const float* __restrict__ bb,
                                             u16* __restrict__ hout, int n) {
    __shared__ u16 act_s[4096];                        // 8 KB: [32 nodes][128 k] swizzled
    __shared__ u16 mid_s[4096];                        // 8 KB
    __shared__ float pA[DIM], pS[DIM], pH[DIM], pB[DIM];
    int tid = threadIdx.x;
    int base = blockIdx.x * 32;

    if (tid < DIM) {
        float s = gg[tid] * rsqrtf(vv[tid] + 1e-5f);
        pS[tid] = s; pH[tid] = be[tid] - mm[tid] * s;
        pA[tid] = ba[tid]; pB[tid] = bb[tid];
    }
    // stage activations (x + agg) -> bf16, swizzled rows
    for (int i = tid; i < 2048; i += 256) {
        int node = i >> 6, ku = i & 63;                // ku: u32 index (2 dims)
        int gnode = base + node;
        float v0 = 0.f, v1 = 0.f;
        if (gnode < n) {
            const u16* row = GATHER ? (xin + ids[gnode] * DIM) : (xin + gnode * DIM);
            u32 xv = *(const u32*)(row + ku * 2);
            u32 av = *(const u32*)(aggbf + gnode * DIM + ku * 2);
            v0 = bf2f((u16)xv) + bf2f((u16)av);
            v1 = bf2f((u16)(xv >> 16)) + bf2f((u16)(av >> 16));
        }
        *(u32*)((char*)act_s + node * 256 + ((4 * ku) ^ ((node & 7) << 4))) = pack2(v0, v1);
    }
    __syncthreads();

    int lane = tid & 63;
    int wv = tid >> 6;
    int fr = lane & 15;                                // output col within tile
    int fq = lane >> 4;                                // k-subgroup / row-group
    int ntb = wv * 2;                                  // first N-tile of this wave
    int xorv = (fr & 7) << 4;
    const char* WA = (const char*)wsa;
    const char* WB = (const char*)wsb;

    f32x4 acc[2][2];
    // ---- phase 1: (act @ wa) + ba -> BN -> ReLU -> mid ----
#pragma unroll
    for (int nt = 0; nt < 2; nt++) {
        float b = pA[(ntb + nt) * 16 + fr];
        f32x4 bb4 = {b, b, b, b};
        acc[0][nt] = bb4; acc[1][nt] = bb4;
    }
#pragma unroll
    for (int kb = 0; kb < 4; kb++) {
        int koff = (kb * 64 + fq * 16) ^ xorv;
        bf16x8 a0 = *(const bf16x8*)((const char*)act_s + fr * 256 + koff);
        bf16x8 a1 = *(const bf16x8*)((const char*)act_s + (16 + fr) * 256 + koff);
        bf16x8 b0 = *(const bf16x8*)(WA + (ntb * 16 + fr) * 256 + koff);
        bf16x8 b1 = *(const bf16x8*)(WA + ((ntb + 1) * 16 + fr) * 256 + koff);
        acc[0][0] = MFMA16(a0, b0, acc[0][0]);
        acc[0][1] = MFMA16(a0, b1, acc[0][1]);
        acc[1][0] = MFMA16(a1, b0, acc[1][0]);
        acc[1][1] = MFMA16(a1, b1, acc[1][1]);
    }
#pragma unroll
    for (int nt = 0; nt < 2; nt++) {
        int j = (ntb + nt) * 16 + fr;
        float sc = pS[j], sh = pH[j];
#pragma unroll
        for (int mt = 0; mt < 2; mt++)
#pragma unroll
            for (int r = 0; r < 4; r++) {
                int node = mt * 16 + fq * 4 + r;
                float v = fmaxf(acc[mt][nt][r] * sc + sh, 0.f);
                *(u16*)((char*)mid_s + node * 256 + ((2 * j) ^ ((node & 7) << 4))) = f2bf(v);
            }
    }
    __syncthreads();
    // ---- phase 2: (mid @ wb) + bb -> ReLU -> hout ----
#pragma unroll
    for (int nt = 0; nt < 2; nt++) {
        float b = pB[(ntb + nt) * 16 + fr];
        f32x4 bb4 = {b, b, b, b};
        acc[0][nt] = bb4; acc[1][nt] = bb4;
    }
#pragma unroll
    for (int kb = 0; kb < 4; kb++) {
        int koff = (kb * 64 + fq * 16) ^ xorv;
        bf16x8 a0 = *(const bf16x8*)((const char*)mid_s + fr * 256 + koff);
        bf16x8 a1 = *(const bf16x8*)((const char*)mid_s + (16 + fr) * 256 + koff);
        bf16x8 b0 = *(const bf16x8*)(WB + (ntb * 16 + fr) * 256 + koff);
        bf16x8 b1 = *(const bf16x8*)(WB + ((ntb + 1) * 16 + fr) * 256 + koff);
        acc[0][0] = MFMA16(a0, b0, acc[0][0]);
        acc[0][1] = MFMA16(a0, b1, acc[0][1]);
        acc[1][0] = MFMA16(a1, b0, acc[1][0]);
        acc[1][1] = MFMA16(a1, b1, acc[1][1]);
    }
#pragma unroll
    for (int nt = 0; nt < 2; nt++) {
        int j = (ntb + nt) * 16 + fr;
#pragma unroll
        for (int mt = 0; mt < 2; mt++)
#pragma unroll
            for (int r = 0; r < 4; r++) {
                int node = base + mt * 16 + fq * 4 + r;
                if (node < n) hout[node * DIM + j] = f2bf(fmaxf(acc[mt][nt][r], 0.f));
            }
    }
}

// ---- pool partials: 8 blocks per graph, each sums an eighth of its nodes ----
__global__ __launch_bounds__(256) void k_pool8(const int* __restrict__ batch,
                                               const u16* __restrict__ h1,
                                               const u16* __restrict__ h2,
                                               float* __restrict__ ppool) {
    int g = blockIdx.x >> 3, part = blockIdx.x & 7;
    int tid = threadIdx.x;
    int lo = 0, hi = N_NODES;
    while (lo < hi) { int m = (lo + hi) >> 1; if (batch[m] < g) lo = m + 1; else hi = m; }
    int start = lo;
    hi = N_NODES;
    while (lo < hi) { int m = (lo + hi) >> 1; if (batch[m] < g + 1) lo = m + 1; else hi = m; }
    int end = lo;
    int len = end - start;
    int qbeg = start + (len * part) / 8;
    int qend = start + (len * (part + 1)) / 8;

    int half = (tid >> 6) & 1;
    int ju = tid & 63;
    int par = tid >> 7;
    const u16* h = half ? h2 : h1;
    float a0 = 0.f, b0 = 0.f, a1 = 0.f, b1 = 0.f;
    float a2 = 0.f, b2 = 0.f, a3 = 0.f, b3 = 0.f;
    int i = qbeg + par;
    for (; i + 6 < qend; i += 8) {
        u32 v0 = *(const u32*)(h + (i    ) * DIM + ju * 2);
        u32 v1 = *(const u32*)(h + (i + 2) * DIM + ju * 2);
        u32 v2 = *(const u32*)(h + (i + 4) * DIM + ju * 2);
        u32 v3 = *(const u32*)(h + (i + 6) * DIM + ju * 2);
        a0 += bf2f((u16)v0); b0 += bf2f((u16)(v0 >> 16));
        a1 += bf2f((u16)v1); b1 += bf2f((u16)(v1 >> 16));
        a2 += bf2f((u16)v2); b2 += bf2f((u16)(v2 >> 16));
        a3 += bf2f((u16)v3); b3 += bf2f((u16)(v3 >> 16));
    }
    for (; i < qend; i += 2) {
        u32 v = *(const u32*)(h + i * DIM + ju * 2);
        a0 += bf2f((u16)v); b0 += bf2f((u16)(v >> 16));
    }
    float sa = (a0 + a1) + (a2 + a3);
    float sb = (b0 + b1) + (b2 + b3);
    __shared__ float2 red[2][128];
    red[par][half * 64 + ju] = make_float2(sa, sb);
    __syncthreads();
    if (tid < 128) {
        float2 r0 = red[0][tid], r1 = red[1][tid];
        ppool[blockIdx.x * 256 + tid * 2]     = r0.x + r1.x;
        ppool[blockIdx.x * 256 + tid * 2 + 1] = r0.y + r1.y;
    }
}

// ---- heads: reduce 8 partials -> relu(@wl1+bl1) -> @wl2+bl2 ------------------
__global__ __launch_bounds__(256) void k_heads(const float* __restrict__ ppool,
                                               const float* __restrict__ wl1,
                                               const float* __restrict__ bl1,
                                               const float* __restrict__ wl2,
                                               const float* __restrict__ bl2,
                                               float* __restrict__ out) {
    int g = blockIdx.x;
    int tid = threadIdx.x;
    __shared__ float pl[256];
    __shared__ float red[256];
    __shared__ float hgs[DIM];
    const float* p = ppool + g * 2048;
    float acc8 = 0.f;
#pragma unroll
    for (int k = 0; k < 8; k++) acc8 += p[k * 256 + tid];
    pl[tid] = acc8;
    __syncthreads();
    // head1: 2 threads per output j
    {
        int j = tid & 127, seg = tid >> 7;
        float acc = 0.f;
        const float* w = wl1 + (seg * 128) * DIM + j;
        const float* q = pl + seg * 128;
#pragma unroll 4
        for (int k = 0; k < 128; k++) acc = fmaf(q[k], w[k * DIM], acc);
        red[tid] = acc;
        __syncthreads();
        if (tid < 128) hgs[tid] = fmaxf(red[tid] + red[tid + 128] + bl1[tid], 0.f);
    }
    __syncthreads();
    if (tid < N_OUT) {
        float acc = bl2[tid];
#pragma unroll 4
        for (int k = 0; k < DIM; k++) acc = fmaf(hgs[k], wl2[k * N_OUT + tid], acc);
        out[g * N_OUT + tid] = acc;
    }
}

extern "C" void kernel_launch(void* const* d_in, const int* in_sizes, int n_in,
                              void* d_out, int out_size, void* d_ws, size_t ws_size,
                              hipStream_t stream) {
    const int* x_ids = (const int*)d_in[0];
    const int* edges = (const int*)d_in[1];
    const int* batch = (const int*)d_in[2];
    const float* emb = (const float*)d_in[3];
    const float *w11 = (const float*)d_in[4],  *b11 = (const float*)d_in[5];
    const float *g1  = (const float*)d_in[6],  *be1 = (const float*)d_in[7];
    const float *m1  = (const float*)d_in[8],  *v1  = (const float*)d_in[9];
    const float *w12 = (const float*)d_in[10], *b12 = (const float*)d_in[11];
    const float *w21 = (const float*)d_in[12], *b21 = (const float*)d_in[13];
    const float *g2  = (const float*)d_in[14], *be2 = (const float*)d_in[15];
    const float *m2  = (const float*)d_in[16], *v2  = (const float*)d_in[17];
    const float *w22 = (const float*)d_in[18], *b22 = (const float*)d_in[19];
    const float *wl1 = (const float*)d_in[20], *bl1 = (const float*)d_in[21];
    const float *wl2 = (const float*)d_in[22], *bl2 = (const float*)d_in[23];

    const int* src = edges;
    const int* dst = edges + N_EDGES;

    float* out_logits = (float*)d_out;                 // [500*10]
    float* xout = (float*)d_out + N_GR * N_OUT;        // [50000*128]

    char* ws = (char*)d_ws;
    u16*   aggbf  = (u16*)ws;                          // 12,800,000 B
    float* ppool  = (float*)(ws + 12800000);           //  4,096,000 B (500*8*256 f32)
    u16*   h1     = (u16*)(ws + 25600000);             // 12,800,000 B
    u16*   h2     = (u16*)(ws + 38400000);             // 12,800,000 B
    // embbf/rank16 alias the h2 region: both dead before k_mlp<false> writes h2
    u16*   embbf  = (u16*)(ws + 38400000);             //    128,000 B
    u16*   rank16 = (u16*)(ws + 38528000);             //  1,600,000 B
    u32*   stat   = (u32*)(ws + 51200000);             //        784 B (lookback flags)
    int*   deg    = (int*)(ws + 51968000);             //    200,000 B
    int*   rowptr = (int*)(ws + 52168000);             //    200,016 B
    u16*   wsz    = (u16*)(ws + 52368016);             //    131,072 B
    u32*   sid    = (u32*)(ws + 52568016);             //  3,200,000 B (ends 55.77 MB)

    u16* wsz1a = wsz;            u16* wsz1b = wsz + 16384;
    u16* wsz2a = wsz + 32768;    u16* wsz2b = wsz + 49152;

    // ---- prep (tables + deg/stat zero), CSR build (gather overlapped) ----
    k_prep<<<449, 256, 0, stream>>>(w11, w12, w21, w22, emb, wsz, embbf, deg, stat);
    k_hist_gather<<<GB_HIST + GB_GATH, 256, 0, stream>>>(dst, deg, rank16, x_ids, emb, xout);
    k_scan<<<NSCANB, 256, 0, stream>>>(deg, rowptr, stat);
    k_fill<<<(N_EDGES + 255) / 256, 256, 0, stream>>>(src, dst, x_ids, rowptr, rank16, sid);

    // ---- layer 1 ----
    k_agg_emb<<<(N_NODES * 64 + 255) / 256, 256, 0, stream>>>(embbf, sid, rowptr, aggbf);
    k_mlp<true><<<(N_NODES + 31) / 32, 256, 0, stream>>>(embbf, x_ids, aggbf, wsz1a, b11, g1, be1, m1, v1, wsz1b, b12, h1, N_NODES);
    // ---- layer 2 ----
    k_agg_bf16<<<(N_NODES * 64 + 255) / 256, 256, 0, stream>>>(h1, rowptr, sid, aggbf);
    k_mlp<false><<<(N_NODES + 31) / 32, 256, 0, stream>>>(h1, nullptr, aggbf, wsz2a, b21, g2, be2, m2, v2, wsz2b, b22, h2, N_NODES);

    // ---- readout ----
    k_pool8<<<N_GR * 8, 256, 0, stream>>>(batch, h1, h2, ppool);
    k_heads<<<N_GR, 256, 0, stream>>>(ppool, wl1, bl1, wl2, bl2, out_logits);
}

// Round 16
// 192.467 us; speedup vs baseline: 1.1852x; 1.1852x over previous
//
#include <hip/hip_runtime.h>
#include <hip/hip_bf16.h>

#define N_NODES 50000
#define N_EDGES 800000
#define DIM 128
#define N_GR 500
#define N_OUT 10

typedef unsigned short u16;
typedef unsigned int u32;
typedef __attribute__((ext_vector_type(8))) short bf16x8;
typedef __attribute__((ext_vector_type(4))) float f32x4;

#define MFMA16(a, b, c) __builtin_amdgcn_mfma_f32_16x16x32_bf16(a, b, c, 0, 0, 0)

__device__ __forceinline__ float bf2f(u16 u) {
    union { u32 i; float f; } c; c.i = ((u32)u) << 16; return c.f;
}
__device__ __forceinline__ u16 f2bf(float f) {
    union { float f; u32 i; } c; c.f = f;
    u32 i = c.i;
    u32 r = i + 0x7FFFu + ((i >> 16) & 1u);
    return (u16)(r >> 16);
}
__device__ __forceinline__ u32 pack2(float a, float b) {
    return (u32)f2bf(a) | ((u32)f2bf(b) << 16);
}

#define GB_HIST 3125                                   // 800000/256
#define GB_GATH 6250                                   // 50000*32/256

// ---- combined: hist (deg+rank) blocks [0,3125) | gather blocks [3125,9375) ----
__global__ __launch_bounds__(256) void k_hist_gather(const int* __restrict__ dst,
                                                     int* __restrict__ deg,
                                                     u16* __restrict__ rank16,
                                                     const int* __restrict__ ids,
                                                     const float* __restrict__ emb,
                                                     float* __restrict__ xout) {
    int b = blockIdx.x;
    if (b < GB_HIST) {
        int e = b * 256 + threadIdx.x;
        if (e >= N_EDGES) return;
        int r = atomicAdd(&deg[dst[e]], 1);
        rank16[e] = (u16)r;
    } else {
        int gid = (b - GB_HIST) * 256 + threadIdx.x;   // N*32 threads
        int node = gid >> 5, seg = gid & 31;
        int id = ids[node];
        f32x4 v = *(const f32x4*)(emb + id * DIM + seg * 4);
        __builtin_nontemporal_store(v, (f32x4*)(xout + node * DIM + seg * 4));
    }
}

__global__ __launch_bounds__(256) void k_scan1(const int* __restrict__ deg, int* __restrict__ bsum) {
    int t = threadIdx.x, b = blockIdx.x;
    int idx = b * 256 + t;
    int v = (idx < N_NODES) ? deg[idx] : 0;
#pragma unroll
    for (int o = 32; o > 0; o >>= 1) v += __shfl_down(v, o, 64);
    __shared__ int wsum[4];
    if ((t & 63) == 0) wsum[t >> 6] = v;
    __syncthreads();
    if (t == 0) bsum[b] = wsum[0] + wsum[1] + wsum[2] + wsum[3];
}

__global__ __launch_bounds__(256) void k_scan2(const int* __restrict__ bsum, int* __restrict__ bpre) {
    __shared__ int s[256];
    int t = threadIdx.x;
    int v = (t < 196) ? bsum[t] : 0;
    s[t] = v; __syncthreads();
    for (int o = 1; o < 256; o <<= 1) {
        int x = (t >= o) ? s[t - o] : 0;
        __syncthreads();
        s[t] += x;
        __syncthreads();
    }
    if (t < 196) bpre[t] = s[t] - v;                   // exclusive prefix
}

__global__ __launch_bounds__(256) void k_scan3(const int* __restrict__ deg,
                                               const int* __restrict__ bpre,
                                               int* __restrict__ rowptr) {
    __shared__ int s[256];
    int t = threadIdx.x, b = blockIdx.x;
    int idx = b * 256 + t;
    int v = (idx < N_NODES) ? deg[idx] : 0;
    s[t] = v; __syncthreads();
    for (int o = 1; o < 256; o <<= 1) {
        int x = (t >= o) ? s[t - o] : 0;
        __syncthreads();
        s[t] += x;
        __syncthreads();
    }
    int ex = bpre[b] + s[t] - v;
    if (idx < N_NODES) rowptr[idx] = ex;
    if (idx == N_NODES - 1) rowptr[N_NODES] = ex + v;
}

// ---- fill (atomic-free): sid[rowptr[dst]+rank] = src | (x_ids[src] << 17) ----
__global__ __launch_bounds__(256) void k_fill(const int* __restrict__ src,
                                              const int* __restrict__ dst,
                                              const int* __restrict__ xids,
                                              const int* __restrict__ rowptr,
                                              const u16* __restrict__ rank16,
                                              u32* __restrict__ sid) {
    int e = blockIdx.x * 256 + threadIdx.x;
    if (e >= N_EDGES) return;
    int s = src[e];
    int pos = rowptr[dst[e]] + rank16[e];
    sid[pos] = (u32)s | ((u32)xids[s] << 17);
}

// ---- prep: weights f32 -> wT bf16 swizzled + emb -> bf16 table + zero deg ----
__global__ __launch_bounds__(256) void k_prep(const float* __restrict__ w11, const float* __restrict__ w12,
                                              const float* __restrict__ w21, const float* __restrict__ w22,
                                              const float* __restrict__ emb,
                                              u16* __restrict__ wout, u16* __restrict__ embbf,
                                              int* __restrict__ deg) {
    int g = blockIdx.x * 256 + threadIdx.x;
    if (g < 4 * 8192) {
        int mat = g >> 13, r = g & 8191;
        int j = r & 127, k0 = (r >> 7) * 2;
        const float* w = (mat == 0) ? w11 : (mat == 1) ? w12 : (mat == 2) ? w21 : w22;
        float v0 = w[k0 * DIM + j];
        float v1 = w[(k0 + 1) * DIM + j];
        char* base = (char*)(wout + mat * 16384);
        *(u32*)(base + j * 256 + ((2 * k0) ^ ((j & 7) << 4))) = pack2(v0, v1);
    } else if (g < 64768) {
        int i = g - 4 * 8192;                          // 0..31999
        float2 p = *(const float2*)(emb + i * 2);
        ((u32*)embbf)[i] = pack2(p.x, p.y);
    } else {
        int i = g - 64768;
        if (i < N_NODES) deg[i] = 0;
    }
}

// ---- layer-1 aggregate from 128 KB embbf table; 8-way ILP, bf16 out ---------
__global__ __launch_bounds__(256) void k_agg_emb(const u16* __restrict__ embbf,
                                                 const u32* __restrict__ sid,
                                                 const int* __restrict__ rowptr,
                                                 u16* __restrict__ aggbf) {
    int wave = (blockIdx.x * 256 + threadIdx.x) >> 6;
    if (wave >= N_NODES) return;
    int lane = threadIdx.x & 63;
    int beg = rowptr[wave], end = rowptr[wave + 1];
    float ax0 = 0.f, ay0 = 0.f, ax1 = 0.f, ay1 = 0.f;
    float ax2 = 0.f, ay2 = 0.f, ax3 = 0.f, ay3 = 0.f;
    int i = beg;
    for (; i + 8 <= end; i += 8) {
        int s0 = sid[i] >> 17,     s1 = sid[i + 1] >> 17;
        int s2 = sid[i + 2] >> 17, s3 = sid[i + 3] >> 17;
        int s4 = sid[i + 4] >> 17, s5 = sid[i + 5] >> 17;
        int s6 = sid[i + 6] >> 17, s7 = sid[i + 7] >> 17;
        u32 v0 = *(const u32*)(embbf + s0 * DIM + lane * 2);
        u32 v1 = *(const u32*)(embbf + s1 * DIM + lane * 2);
        u32 v2 = *(const u32*)(embbf + s2 * DIM + lane * 2);
        u32 v3 = *(const u32*)(embbf + s3 * DIM + lane * 2);
        u32 v4 = *(const u32*)(embbf + s4 * DIM + lane * 2);
        u32 v5 = *(const u32*)(embbf + s5 * DIM + lane * 2);
        u32 v6 = *(const u32*)(embbf + s6 * DIM + lane * 2);
        u32 v7 = *(const u32*)(embbf + s7 * DIM + lane * 2);
        ax0 += bf2f((u16)v0) + bf2f((u16)v4); ay0 += bf2f((u16)(v0 >> 16)) + bf2f((u16)(v4 >> 16));
        ax1 += bf2f((u16)v1) + bf2f((u16)v5); ay1 += bf2f((u16)(v1 >> 16)) + bf2f((u16)(v5 >> 16));
        ax2 += bf2f((u16)v2) + bf2f((u16)v6); ay2 += bf2f((u16)(v2 >> 16)) + bf2f((u16)(v6 >> 16));
        ax3 += bf2f((u16)v3) + bf2f((u16)v7); ay3 += bf2f((u16)(v3 >> 16)) + bf2f((u16)(v7 >> 16));
    }
    for (; i + 4 <= end; i += 4) {
        int s0 = sid[i] >> 17, s1 = sid[i + 1] >> 17, s2 = sid[i + 2] >> 17, s3 = sid[i + 3] >> 17;
        u32 v0 = *(const u32*)(embbf + s0 * DIM + lane * 2);
        u32 v1 = *(const u32*)(embbf + s1 * DIM + lane * 2);
        u32 v2 = *(const u32*)(embbf + s2 * DIM + lane * 2);
        u32 v3 = *(const u32*)(embbf + s3 * DIM + lane * 2);
        ax0 += bf2f((u16)v0); ay0 += bf2f((u16)(v0 >> 16));
        ax1 += bf2f((u16)v1); ay1 += bf2f((u16)(v1 >> 16));
        ax2 += bf2f((u16)v2); ay2 += bf2f((u16)(v2 >> 16));
        ax3 += bf2f((u16)v3); ay3 += bf2f((u16)(v3 >> 16));
    }
    for (; i < end; i++) {
        int s = sid[i] >> 17;
        u32 v = *(const u32*)(embbf + s * DIM + lane * 2);
        ax0 += bf2f((u16)v); ay0 += bf2f((u16)(v >> 16));
    }
    float ax = (ax0 + ax1) + (ax2 + ax3);
    float ay = (ay0 + ay1) + (ay2 + ay3);
    *(u32*)(aggbf + wave * DIM + lane * 2) = pack2(ax, ay);
}

// ---- layer-2 aggregate from h1; 8-way ILP, bf16 out -------------------------
__global__ __launch_bounds__(256) void k_agg_bf16(const u16* __restrict__ x,
                                                  const int* __restrict__ rowptr,
                                                  const u32* __restrict__ sid,
                                                  u16* __restrict__ aggbf) {
    int wave = (blockIdx.x * 256 + threadIdx.x) >> 6;
    if (wave >= N_NODES) return;
    int lane = threadIdx.x & 63;
    int beg = rowptr[wave], end = rowptr[wave + 1];
    float ax0 = 0.f, ay0 = 0.f, ax1 = 0.f, ay1 = 0.f;
    float ax2 = 0.f, ay2 = 0.f, ax3 = 0.f, ay3 = 0.f;
    int i = beg;
    for (; i + 8 <= end; i += 8) {
        int s0 = sid[i] & 0x1FFFF,     s1 = sid[i + 1] & 0x1FFFF;
        int s2 = sid[i + 2] & 0x1FFFF, s3 = sid[i + 3] & 0x1FFFF;
        int s4 = sid[i + 4] & 0x1FFFF, s5 = sid[i + 5] & 0x1FFFF;
        int s6 = sid[i + 6] & 0x1FFFF, s7 = sid[i + 7] & 0x1FFFF;
        u32 v0 = *(const u32*)(x + s0 * DIM + lane * 2);
        u32 v1 = *(const u32*)(x + s1 * DIM + lane * 2);
        u32 v2 = *(const u32*)(x + s2 * DIM + lane * 2);
        u32 v3 = *(const u32*)(x + s3 * DIM + lane * 2);
        u32 v4 = *(const u32*)(x + s4 * DIM + lane * 2);
        u32 v5 = *(const u32*)(x + s5 * DIM + lane * 2);
        u32 v6 = *(const u32*)(x + s6 * DIM + lane * 2);
        u32 v7 = *(const u32*)(x + s7 * DIM + lane * 2);
        ax0 += bf2f((u16)v0) + bf2f((u16)v4); ay0 += bf2f((u16)(v0 >> 16)) + bf2f((u16)(v4 >> 16));
        ax1 += bf2f((u16)v1) + bf2f((u16)v5); ay1 += bf2f((u16)(v1 >> 16)) + bf2f((u16)(v5 >> 16));
        ax2 += bf2f((u16)v2) + bf2f((u16)v6); ay2 += bf2f((u16)(v2 >> 16)) + bf2f((u16)(v6 >> 16));
        ax3 += bf2f((u16)v3) + bf2f((u16)v7); ay3 += bf2f((u16)(v3 >> 16)) + bf2f((u16)(v7 >> 16));
    }
    for (; i + 4 <= end; i += 4) {
        int s0 = sid[i] & 0x1FFFF, s1 = sid[i + 1] & 0x1FFFF;
        int s2 = sid[i + 2] & 0x1FFFF, s3 = sid[i + 3] & 0x1FFFF;
        u32 v0 = *(const u32*)(x + s0 * DIM + lane * 2);
        u32 v1 = *(const u32*)(x + s1 * DIM + lane * 2);
        u32 v2 = *(const u32*)(x + s2 * DIM + lane * 2);
        u32 v3 = *(const u32*)(x + s3 * DIM + lane * 2);
        ax0 += bf2f((u16)v0); ay0 += bf2f((u16)(v0 >> 16));
        ax1 += bf2f((u16)v1); ay1 += bf2f((u16)(v1 >> 16));
        ax2 += bf2f((u16)v2); ay2 += bf2f((u16)(v2 >> 16));
        ax3 += bf2f((u16)v3); ay3 += bf2f((u16)(v3 >> 16));
    }
    for (; i < end; i++) {
        int s = sid[i] & 0x1FFFF;
        u32 v = *(const u32*)(x + s * DIM + lane * 2);
        ax0 += bf2f((u16)v); ay0 += bf2f((u16)(v >> 16));
    }
    float ax = (ax0 + ax1) + (ax2 + ax3);
    float ay = (ay0 + ay1) + (ay2 + ay3);
    *(u32*)(aggbf + wave * DIM + lane * 2) = pack2(ax, ay);
}

// ------- fused GIN MLP via MFMA; B-fragments read DIRECTLY from L2-hot global -------
template<bool GATHER>
__global__ __launch_bounds__(256) void k_mlp(const u16* __restrict__ xin,
                                             const int* __restrict__ ids,
                                             const u16* __restrict__ aggbf,
                                             const u16* __restrict__ wsa, const float* __restrict__ ba,
                                             const float* __restrict__ gg, const float* __restrict__ be,
                                             const float* __restrict__ mm, const float* __restrict__ vv,
                                             const u16* __restrict__ wsb, const float* __restrict__ bb,
                                             u16* __restrict__ hout, int n) {
    __shared__ u16 act_s[4096];                        // 8 KB: [32 nodes][128 k] swizzled
    __shared__ u16 mid_s[4096];                        // 8 KB
    __shared__ float pA[DIM], pS[DIM], pH[DIM], pB[DIM];
    int tid = threadIdx.x;
    int base = blockIdx.x * 32;

    if (tid < DIM) {
        float s = gg[tid] * rsqrtf(vv[tid] + 1e-5f);
        pS[tid] = s; pH[tid] = be[tid] - mm[tid] * s;
        pA[tid] = ba[tid]; pB[tid] = bb[tid];
    }
    // stage activations (x + agg) -> bf16, swizzled rows
    for (int i = tid; i < 2048; i += 256) {
        int node = i >> 6, ku = i & 63;                // ku: u32 index (2 dims)
        int gnode = base + node;
        float v0 = 0.f, v1 = 0.f;
        if (gnode < n) {
            const u16* row = GATHER ? (xin + ids[gnode] * DIM) : (xin + gnode * DIM);
            u32 xv = *(const u32*)(row + ku * 2);
            u32 av = *(const u32*)(aggbf + gnode * DIM + ku * 2);
            v0 = bf2f((u16)xv) + bf2f((u16)av);
            v1 = bf2f((u16)(xv >> 16)) + bf2f((u16)(av >> 16));
        }
        *(u32*)((char*)act_s + node * 256 + ((4 * ku) ^ ((node & 7) << 4))) = pack2(v0, v1);
    }
    __syncthreads();

    int lane = tid & 63;
    int wv = tid >> 6;
    int fr = lane & 15;                                // output col within tile
    int fq = lane >> 4;                                // k-subgroup / row-group
    int ntb = wv * 2;                                  // first N-tile of this wave
    int xorv = (fr & 7) << 4;
    const char* WA = (const char*)wsa;
    const char* WB = (const char*)wsb;

    f32x4 acc[2][2];
    // ---- phase 1: (act @ wa) + ba -> BN -> ReLU -> mid ----
#pragma unroll
    for (int nt = 0; nt < 2; nt++) {
        float b = pA[(ntb + nt) * 16 + fr];
        f32x4 bb4 = {b, b, b, b};
        acc[0][nt] = bb4; acc[1][nt] = bb4;
    }
#pragma unroll
    for (int kb = 0; kb < 4; kb++) {
        int koff = (kb * 64 + fq * 16) ^ xorv;
        bf16x8 a0 = *(const bf16x8*)((const char*)act_s + fr * 256 + koff);
        bf16x8 a1 = *(const bf16x8*)((const char*)act_s + (16 + fr) * 256 + koff);
        bf16x8 b0 = *(const bf16x8*)(WA + (ntb * 16 + fr) * 256 + koff);
        bf16x8 b1 = *(const bf16x8*)(WA + ((ntb + 1) * 16 + fr) * 256 + koff);
        acc[0][0] = MFMA16(a0, b0, acc[0][0]);
        acc[0][1] = MFMA16(a0, b1, acc[0][1]);
        acc[1][0] = MFMA16(a1, b0, acc[1][0]);
        acc[1][1] = MFMA16(a1, b1, acc[1][1]);
    }
#pragma unroll
    for (int nt = 0; nt < 2; nt++) {
        int j = (ntb + nt) * 16 + fr;
        float sc = pS[j], sh = pH[j];
#pragma unroll
        for (int mt = 0; mt < 2; mt++)
#pragma unroll
            for (int r = 0; r < 4; r++) {
                int node = mt * 16 + fq * 4 + r;
                float v = fmaxf(acc[mt][nt][r] * sc + sh, 0.f);
                *(u16*)((char*)mid_s + node * 256 + ((2 * j) ^ ((node & 7) << 4))) = f2bf(v);
            }
    }
    __syncthreads();
    // ---- phase 2: (mid @ wb) + bb -> ReLU -> hout ----
#pragma unroll
    for (int nt = 0; nt < 2; nt++) {
        float b = pB[(ntb + nt) * 16 + fr];
        f32x4 bb4 = {b, b, b, b};
        acc[0][nt] = bb4; acc[1][nt] = bb4;
    }
#pragma unroll
    for (int kb = 0; kb < 4; kb++) {
        int koff = (kb * 64 + fq * 16) ^ xorv;
        bf16x8 a0 = *(const bf16x8*)((const char*)mid_s + fr * 256 + koff);
        bf16x8 a1 = *(const bf16x8*)((const char*)mid_s + (16 + fr) * 256 + koff);
        bf16x8 b0 = *(const bf16x8*)(WB + (ntb * 16 + fr) * 256 + koff);
        bf16x8 b1 = *(const bf16x8*)(WB + ((ntb + 1) * 16 + fr) * 256 + koff);
        acc[0][0] = MFMA16(a0, b0, acc[0][0]);
        acc[0][1] = MFMA16(a0, b1, acc[0][1]);
        acc[1][0] = MFMA16(a1, b0, acc[1][0]);
        acc[1][1] = MFMA16(a1, b1, acc[1][1]);
    }
#pragma unroll
    for (int nt = 0; nt < 2; nt++) {
        int j = (ntb + nt) * 16 + fr;
#pragma unroll
        for (int mt = 0; mt < 2; mt++)
#pragma unroll
            for (int r = 0; r < 4; r++) {
                int node = base + mt * 16 + fq * 4 + r;
                if (node < n) hout[node * DIM + j] = f2bf(fmaxf(acc[mt][nt][r], 0.f));
            }
    }
}

// ---- pool partials: 8 blocks per graph, each sums an eighth of its nodes ----
__global__ __launch_bounds__(256) void k_pool8(const int* __restrict__ batch,
                                               const u16* __restrict__ h1,
                                               const u16* __restrict__ h2,
                                               float* __restrict__ ppool) {
    int g = blockIdx.x >> 3, part = blockIdx.x & 7;
    int tid = threadIdx.x;
    int lo = 0, hi = N_NODES;
    while (lo < hi) { int m = (lo + hi) >> 1; if (batch[m] < g) lo = m + 1; else hi = m; }
    int start = lo;
    hi = N_NODES;
    while (lo < hi) { int m = (lo + hi) >> 1; if (batch[m] < g + 1) lo = m + 1; else hi = m; }
    int end = lo;
    int len = end - start;
    int qbeg = start + (len * part) / 8;
    int qend = start + (len * (part + 1)) / 8;

    int half = (tid >> 6) & 1;
    int ju = tid & 63;
    int par = tid >> 7;
    const u16* h = half ? h2 : h1;
    float a0 = 0.f, b0 = 0.f, a1 = 0.f, b1 = 0.f;
    float a2 = 0.f, b2 = 0.f, a3 = 0.f, b3 = 0.f;
    int i = qbeg + par;
    for (; i + 6 < qend; i += 8) {
        u32 v0 = *(const u32*)(h + (i    ) * DIM + ju * 2);
        u32 v1 = *(const u32*)(h + (i + 2) * DIM + ju * 2);
        u32 v2 = *(const u32*)(h + (i + 4) * DIM + ju * 2);
        u32 v3 = *(const u32*)(h + (i + 6) * DIM + ju * 2);
        a0 += bf2f((u16)v0); b0 += bf2f((u16)(v0 >> 16));
        a1 += bf2f((u16)v1); b1 += bf2f((u16)(v1 >> 16));
        a2 += bf2f((u16)v2); b2 += bf2f((u16)(v2 >> 16));
        a3 += bf2f((u16)v3); b3 += bf2f((u16)(v3 >> 16));
    }
    for (; i < qend; i += 2) {
        u32 v = *(const u32*)(h + i * DIM + ju * 2);
        a0 += bf2f((u16)v); b0 += bf2f((u16)(v >> 16));
    }
    float sa = (a0 + a1) + (a2 + a3);
    float sb = (b0 + b1) + (b2 + b3);
    __shared__ float2 red[2][128];
    red[par][half * 64 + ju] = make_float2(sa, sb);
    __syncthreads();
    if (tid < 128) {
        float2 r0 = red[0][tid], r1 = red[1][tid];
        ppool[blockIdx.x * 256 + tid * 2]     = r0.x + r1.x;
        ppool[blockIdx.x * 256 + tid * 2 + 1] = r0.y + r1.y;
    }
}

// ---- heads: reduce 8 partials -> relu(@wl1+bl1) -> @wl2+bl2 ------------------
__global__ __launch_bounds__(256) void k_heads(const float* __restrict__ ppool,
                                               const float* __restrict__ wl1,
                                               const float* __restrict__ bl1,
                                               const float* __restrict__ wl2,
                                               const float* __restrict__ bl2,
                                               float* __restrict__ out) {
    int g = blockIdx.x;
    int tid = threadIdx.x;
    __shared__ float pl[256];
    __shared__ float red[256];
    __shared__ float hgs[DIM];
    const float* p = ppool + g * 2048;
    float acc8 = 0.f;
#pragma unroll
    for (int k = 0; k < 8; k++) acc8 += p[k * 256 + tid];
    pl[tid] = acc8;
    __syncthreads();
    // head1: 2 threads per output j
    {
        int j = tid & 127, seg = tid >> 7;
        float acc = 0.f;
        const float* w = wl1 + (seg * 128) * DIM + j;
        const float* q = pl + seg * 128;
#pragma unroll 4
        for (int k = 0; k < 128; k++) acc = fmaf(q[k], w[k * DIM], acc);
        red[tid] = acc;
        __syncthreads();
        if (tid < 128) hgs[tid] = fmaxf(red[tid] + red[tid + 128] + bl1[tid], 0.f);
    }
    __syncthreads();
    if (tid < N_OUT) {
        float acc = bl2[tid];
#pragma unroll 4
        for (int k = 0; k < DIM; k++) acc = fmaf(hgs[k], wl2[k * N_OUT + tid], acc);
        out[g * N_OUT + tid] = acc;
    }
}

extern "C" void kernel_launch(void* const* d_in, const int* in_sizes, int n_in,
                              void* d_out, int out_size, void* d_ws, size_t ws_size,
                              hipStream_t stream) {
    const int* x_ids = (const int*)d_in[0];
    const int* edges = (const int*)d_in[1];
    const int* batch = (const int*)d_in[2];
    const float* emb = (const float*)d_in[3];
    const float *w11 = (const float*)d_in[4],  *b11 = (const float*)d_in[5];
    const float *g1  = (const float*)d_in[6],  *be1 = (const float*)d_in[7];
    const float *m1  = (const float*)d_in[8],  *v1  = (const float*)d_in[9];
    const float *w12 = (const float*)d_in[10], *b12 = (const float*)d_in[11];
    const float *w21 = (const float*)d_in[12], *b21 = (const float*)d_in[13];
    const float *g2  = (const float*)d_in[14], *be2 = (const float*)d_in[15];
    const float *m2  = (const float*)d_in[16], *v2  = (const float*)d_in[17];
    const float *w22 = (const float*)d_in[18], *b22 = (const float*)d_in[19];
    const float *wl1 = (const float*)d_in[20], *bl1 = (const float*)d_in[21];
    const float *wl2 = (const float*)d_in[22], *bl2 = (const float*)d_in[23];

    const int* src = edges;
    const int* dst = edges + N_EDGES;

    float* out_logits = (float*)d_out;                 // [500*10]
    float* xout = (float*)d_out + N_GR * N_OUT;        // [50000*128]

    char* ws = (char*)d_ws;
    u16*   aggbf  = (u16*)ws;                          // 12,800,000 B
    float* ppool  = (float*)(ws + 12800000);           //  4,096,000 B (500*8*256 f32)
    u16*   h1     = (u16*)(ws + 25600000);             // 12,800,000 B
    u16*   h2     = (u16*)(ws + 38400000);             // 12,800,000 B
    // embbf/rank16 alias the h2 region: both dead before k_mlp<false> writes h2
    u16*   embbf  = (u16*)(ws + 38400000);             //    128,000 B
    u16*   rank16 = (u16*)(ws + 38528000);             //  1,600,000 B
    int*   bsum   = (int*)(ws + 51200000);
    int*   bpre   = (int*)(ws + 51204096);
    int*   deg    = (int*)(ws + 51968000);             //    200,000 B
    int*   rowptr = (int*)(ws + 52168000);             //    200,016 B
    u16*   wsz    = (u16*)(ws + 52368016);             //    131,072 B
    u32*   sid    = (u32*)(ws + 52568016);             //  3,200,000 B (ends 55.77 MB)

    u16* wsz1a = wsz;            u16* wsz1b = wsz + 16384;
    u16* wsz2a = wsz + 32768;    u16* wsz2b = wsz + 49152;

    // ---- prep (tables + deg zero), CSR build (gather overlapped) ----
    k_prep<<<449, 256, 0, stream>>>(w11, w12, w21, w22, emb, wsz, embbf, deg);
    k_hist_gather<<<GB_HIST + GB_GATH, 256, 0, stream>>>(dst, deg, rank16, x_ids, emb, xout);
    k_scan1<<<196, 256, 0, stream>>>(deg, bsum);
    k_scan2<<<1, 256, 0, stream>>>(bsum, bpre);
    k_scan3<<<196, 256, 0, stream>>>(deg, bpre, rowptr);
    k_fill<<<(N_EDGES + 255) / 256, 256, 0, stream>>>(src, dst, x_ids, rowptr, rank16, sid);

    // ---- layer 1 ----
    k_agg_emb<<<(N_NODES * 64 + 255) / 256, 256, 0, stream>>>(embbf, sid, rowptr, aggbf);
    k_mlp<true><<<(N_NODES + 31) / 32, 256, 0, stream>>>(embbf, x_ids, aggbf, wsz1a, b11, g1, be1, m1, v1, wsz1b, b12, h1, N_NODES);
    // ---- layer 2 ----
    k_agg_bf16<<<(N_NODES * 64 + 255) / 256, 256, 0, stream>>>(h1, rowptr, sid, aggbf);
    k_mlp<false><<<(N_NODES + 31) / 32, 256, 0, stream>>>(h1, nullptr, aggbf, wsz2a, b21, g2, be2, m2, v2, wsz2b, b22, h2, N_NODES);

    // ---- readout ----
    k_pool8<<<N_GR * 8, 256, 0, stream>>>(batch, h1, h2, ppool);
    k_heads<<<N_GR, 256, 0, stream>>>(ppool, wl1, bl1, wl2, bl2, out_logits);
}

// Round 17
// 186.069 us; speedup vs baseline: 1.2260x; 1.0344x over previous
//
#include <hip/hip_runtime.h>
#include <hip/hip_bf16.h>

#define N_NODES 50000
#define N_EDGES 800000
#define DIM 128
#define N_GR 500
#define N_OUT 10

typedef unsigned short u16;
typedef unsigned int u32;
typedef __attribute__((ext_vector_type(8))) short bf16x8;
typedef __attribute__((ext_vector_type(4))) float f32x4;

#define MFMA16(a, b, c) __builtin_amdgcn_mfma_f32_16x16x32_bf16(a, b, c, 0, 0, 0)

__device__ __forceinline__ float bf2f(u16 u) {
    union { u32 i; float f; } c; c.i = ((u32)u) << 16; return c.f;
}
__device__ __forceinline__ u16 f2bf(float f) {
    union { float f; u32 i; } c; c.f = f;
    u32 i = c.i;
    u32 r = i + 0x7FFFu + ((i >> 16) & 1u);
    return (u16)(r >> 16);
}
__device__ __forceinline__ u32 pack2(float a, float b) {
    return (u32)f2bf(a) | ((u32)f2bf(b) << 16);
}

#define GB_HIST 3125                                   // 800000/256
#define GB_GATH 6250                                   // 50000*32/256

// ---- combined: hist (deg+rank) blocks [0,3125) | gather blocks [3125,9375) ----
__global__ __launch_bounds__(256) void k_hist_gather(const int* __restrict__ dst,
                                                     int* __restrict__ deg,
                                                     u16* __restrict__ rank16,
                                                     const int* __restrict__ ids,
                                                     const float* __restrict__ emb,
                                                     float* __restrict__ xout) {
    int b = blockIdx.x;
    if (b < GB_HIST) {
        int e = b * 256 + threadIdx.x;
        if (e >= N_EDGES) return;
        int r = atomicAdd(&deg[dst[e]], 1);
        rank16[e] = (u16)r;
    } else {
        int gid = (b - GB_HIST) * 256 + threadIdx.x;   // N*32 threads
        int node = gid >> 5, seg = gid & 31;
        int id = ids[node];
        f32x4 v = *(const f32x4*)(emb + id * DIM + seg * 4);
        __builtin_nontemporal_store(v, (f32x4*)(xout + node * DIM + seg * 4));
    }
}

__global__ __launch_bounds__(256) void k_scan1(const int* __restrict__ deg, int* __restrict__ bsum) {
    int t = threadIdx.x, b = blockIdx.x;
    int idx = b * 256 + t;
    int v = (idx < N_NODES) ? deg[idx] : 0;
#pragma unroll
    for (int o = 32; o > 0; o >>= 1) v += __shfl_down(v, o, 64);
    __shared__ int wsum[4];
    if ((t & 63) == 0) wsum[t >> 6] = v;
    __syncthreads();
    if (t == 0) bsum[b] = wsum[0] + wsum[1] + wsum[2] + wsum[3];
}

__global__ __launch_bounds__(256) void k_scan2(const int* __restrict__ bsum, int* __restrict__ bpre) {
    __shared__ int s[256];
    int t = threadIdx.x;
    int v = (t < 196) ? bsum[t] : 0;
    s[t] = v; __syncthreads();
    for (int o = 1; o < 256; o <<= 1) {
        int x = (t >= o) ? s[t - o] : 0;
        __syncthreads();
        s[t] += x;
        __syncthreads();
    }
    if (t < 196) bpre[t] = s[t] - v;                   // exclusive prefix
}

__global__ __launch_bounds__(256) void k_scan3(const int* __restrict__ deg,
                                               const int* __restrict__ bpre,
                                               int* __restrict__ rowptr) {
    __shared__ int s[256];
    int t = threadIdx.x, b = blockIdx.x;
    int idx = b * 256 + t;
    int v = (idx < N_NODES) ? deg[idx] : 0;
    s[t] = v; __syncthreads();
    for (int o = 1; o < 256; o <<= 1) {
        int x = (t >= o) ? s[t - o] : 0;
        __syncthreads();
        s[t] += x;
        __syncthreads();
    }
    int ex = bpre[b] + s[t] - v;
    if (idx < N_NODES) rowptr[idx] = ex;
    if (idx == N_NODES - 1) rowptr[N_NODES] = ex + v;
}

// ---- fill (atomic-free): sid[rowptr[dst]+rank] = src | (x_ids[src] << 17) ----
__global__ __launch_bounds__(256) void k_fill(const int* __restrict__ src,
                                              const int* __restrict__ dst,
                                              const int* __restrict__ xids,
                                              const int* __restrict__ rowptr,
                                              const u16* __restrict__ rank16,
                                              u32* __restrict__ sid) {
    int e = blockIdx.x * 256 + threadIdx.x;
    if (e >= N_EDGES) return;
    int s = src[e];
    int pos = rowptr[dst[e]] + rank16[e];
    sid[pos] = (u32)s | ((u32)xids[s] << 17);
}

// ---- prep: weights f32 -> wT bf16 swizzled + emb -> bf16 table + zero deg ----
__global__ __launch_bounds__(256) void k_prep(const float* __restrict__ w11, const float* __restrict__ w12,
                                              const float* __restrict__ w21, const float* __restrict__ w22,
                                              const float* __restrict__ emb,
                                              u16* __restrict__ wout, u16* __restrict__ embbf,
                                              int* __restrict__ deg) {
    int g = blockIdx.x * 256 + threadIdx.x;
    if (g < 4 * 8192) {
        int mat = g >> 13, r = g & 8191;
        int j = r & 127, k0 = (r >> 7) * 2;
        const float* w = (mat == 0) ? w11 : (mat == 1) ? w12 : (mat == 2) ? w21 : w22;
        float v0 = w[k0 * DIM + j];
        float v1 = w[(k0 + 1) * DIM + j];
        char* base = (char*)(wout + mat * 16384);
        *(u32*)(base + j * 256 + ((2 * k0) ^ ((j & 7) << 4))) = pack2(v0, v1);
    } else if (g < 64768) {
        int i = g - 4 * 8192;                          // 0..31999
        float2 p = *(const float2*)(emb + i * 2);
        ((u32*)embbf)[i] = pack2(p.x, p.y);
    } else {
        int i = g - 64768;
        if (i < N_NODES) deg[i] = 0;
    }
}

// ------- fused GIN layer: CSR aggregate (8-way ILP) + MLP via MFMA -------
// Retry of round-11 fusion: now only 18 KB LDS (weights from L2-hot global),
// so the latency-bound gather phase runs at ~5-6 blocks/CU, not 2.
// Block = 32 nodes, 4 waves; each wave stages 8 nodes (wv*8..wv*8+7).
template<bool L1>
__global__ __launch_bounds__(256) void k_mlp(const u16* __restrict__ xin,
                                             const int* __restrict__ ids,
                                             const u32* __restrict__ sid,
                                             const int* __restrict__ rowptr,
                                             const u16* __restrict__ wsa, const float* __restrict__ ba,
                                             const float* __restrict__ gg, const float* __restrict__ be,
                                             const float* __restrict__ mm, const float* __restrict__ vv,
                                             const u16* __restrict__ wsb, const float* __restrict__ bb,
                                             u16* __restrict__ hout, int n) {
    __shared__ u16 act_s[4096];                        // 8 KB: [32 nodes][128 k] swizzled
    __shared__ u16 mid_s[4096];                        // 8 KB
    __shared__ float pA[DIM], pS[DIM], pH[DIM], pB[DIM];
    int tid = threadIdx.x;
    int base = blockIdx.x * 32;

    if (tid < DIM) {
        float s = gg[tid] * rsqrtf(vv[tid] + 1e-5f);
        pS[tid] = s; pH[tid] = be[tid] - mm[tid] * s;
        pA[tid] = ba[tid]; pB[tid] = bb[tid];
    }

    int lane = tid & 63;
    int wv = tid >> 6;

    // ---- fused aggregate + staging: wave wv owns nodes wv*8 .. wv*8+7 ----
#pragma unroll
    for (int t = 0; t < 8; t++) {
        int node = wv * 8 + t;
        int gnode = base + node;
        float ax0 = 0.f, ay0 = 0.f, ax1 = 0.f, ay1 = 0.f;
        float ax2 = 0.f, ay2 = 0.f, ax3 = 0.f, ay3 = 0.f;
        if (gnode < n) {
            int beg = rowptr[gnode], end = rowptr[gnode + 1];
            int i = beg;
            for (; i + 8 <= end; i += 8) {
                u32 e0 = sid[i],     e1 = sid[i + 1], e2 = sid[i + 2], e3 = sid[i + 3];
                u32 e4 = sid[i + 4], e5 = sid[i + 5], e6 = sid[i + 6], e7 = sid[i + 7];
                int s0 = L1 ? (int)(e0 >> 17) : (int)(e0 & 0x1FFFF);
                int s1 = L1 ? (int)(e1 >> 17) : (int)(e1 & 0x1FFFF);
                int s2 = L1 ? (int)(e2 >> 17) : (int)(e2 & 0x1FFFF);
                int s3 = L1 ? (int)(e3 >> 17) : (int)(e3 & 0x1FFFF);
                int s4 = L1 ? (int)(e4 >> 17) : (int)(e4 & 0x1FFFF);
                int s5 = L1 ? (int)(e5 >> 17) : (int)(e5 & 0x1FFFF);
                int s6 = L1 ? (int)(e6 >> 17) : (int)(e6 & 0x1FFFF);
                int s7 = L1 ? (int)(e7 >> 17) : (int)(e7 & 0x1FFFF);
                u32 v0 = *(const u32*)(xin + s0 * DIM + lane * 2);
                u32 v1 = *(const u32*)(xin + s1 * DIM + lane * 2);
                u32 v2 = *(const u32*)(xin + s2 * DIM + lane * 2);
                u32 v3 = *(const u32*)(xin + s3 * DIM + lane * 2);
                u32 v4 = *(const u32*)(xin + s4 * DIM + lane * 2);
                u32 v5 = *(const u32*)(xin + s5 * DIM + lane * 2);
                u32 v6 = *(const u32*)(xin + s6 * DIM + lane * 2);
                u32 v7 = *(const u32*)(xin + s7 * DIM + lane * 2);
                ax0 += bf2f((u16)v0) + bf2f((u16)v4); ay0 += bf2f((u16)(v0 >> 16)) + bf2f((u16)(v4 >> 16));
                ax1 += bf2f((u16)v1) + bf2f((u16)v5); ay1 += bf2f((u16)(v1 >> 16)) + bf2f((u16)(v5 >> 16));
                ax2 += bf2f((u16)v2) + bf2f((u16)v6); ay2 += bf2f((u16)(v2 >> 16)) + bf2f((u16)(v6 >> 16));
                ax3 += bf2f((u16)v3) + bf2f((u16)v7); ay3 += bf2f((u16)(v3 >> 16)) + bf2f((u16)(v7 >> 16));
            }
            for (; i + 4 <= end; i += 4) {
                u32 e0 = sid[i], e1 = sid[i + 1], e2 = sid[i + 2], e3 = sid[i + 3];
                int s0 = L1 ? (int)(e0 >> 17) : (int)(e0 & 0x1FFFF);
                int s1 = L1 ? (int)(e1 >> 17) : (int)(e1 & 0x1FFFF);
                int s2 = L1 ? (int)(e2 >> 17) : (int)(e2 & 0x1FFFF);
                int s3 = L1 ? (int)(e3 >> 17) : (int)(e3 & 0x1FFFF);
                u32 v0 = *(const u32*)(xin + s0 * DIM + lane * 2);
                u32 v1 = *(const u32*)(xin + s1 * DIM + lane * 2);
                u32 v2 = *(const u32*)(xin + s2 * DIM + lane * 2);
                u32 v3 = *(const u32*)(xin + s3 * DIM + lane * 2);
                ax0 += bf2f((u16)v0); ay0 += bf2f((u16)(v0 >> 16));
                ax1 += bf2f((u16)v1); ay1 += bf2f((u16)(v1 >> 16));
                ax2 += bf2f((u16)v2); ay2 += bf2f((u16)(v2 >> 16));
                ax3 += bf2f((u16)v3); ay3 += bf2f((u16)(v3 >> 16));
            }
            for (; i < end; i++) {
                u32 e = sid[i];
                int s = L1 ? (int)(e >> 17) : (int)(e & 0x1FFFF);
                u32 v = *(const u32*)(xin + s * DIM + lane * 2);
                ax0 += bf2f((u16)v); ay0 += bf2f((u16)(v >> 16));
            }
            // own row: L1: embbf[ids[i]], L2: h1[i]
            const u16* row = L1 ? (xin + ids[gnode] * DIM) : (xin + gnode * DIM);
            u32 xv = *(const u32*)(row + lane * 2);
            ax0 += bf2f((u16)xv); ay0 += bf2f((u16)(xv >> 16));
        }
        float ax = (ax0 + ax1) + (ax2 + ax3);
        float ay = (ay0 + ay1) + (ay2 + ay3);
        *(u32*)((char*)act_s + node * 256 + ((4 * lane) ^ ((node & 7) << 4))) = pack2(ax, ay);
    }
    __syncthreads();

    int fr = lane & 15;                                // output col within tile
    int fq = lane >> 4;                                // k-subgroup / row-group
    int ntb = wv * 2;                                  // first N-tile of this wave
    int xorv = (fr & 7) << 4;
    const char* WA = (const char*)wsa;
    const char* WB = (const char*)wsb;

    f32x4 acc[2][2];
    // ---- phase 1: (act @ wa) + ba -> BN -> ReLU -> mid ----
#pragma unroll
    for (int nt = 0; nt < 2; nt++) {
        float b = pA[(ntb + nt) * 16 + fr];
        f32x4 bb4 = {b, b, b, b};
        acc[0][nt] = bb4; acc[1][nt] = bb4;
    }
#pragma unroll
    for (int kb = 0; kb < 4; kb++) {
        int koff = (kb * 64 + fq * 16) ^ xorv;
        bf16x8 a0 = *(const bf16x8*)((const char*)act_s + fr * 256 + koff);
        bf16x8 a1 = *(const bf16x8*)((const char*)act_s + (16 + fr) * 256 + koff);
        bf16x8 b0 = *(const bf16x8*)(WA + (ntb * 16 + fr) * 256 + koff);
        bf16x8 b1 = *(const bf16x8*)(WA + ((ntb + 1) * 16 + fr) * 256 + koff);
        acc[0][0] = MFMA16(a0, b0, acc[0][0]);
        acc[0][1] = MFMA16(a0, b1, acc[0][1]);
        acc[1][0] = MFMA16(a1, b0, acc[1][0]);
        acc[1][1] = MFMA16(a1, b1, acc[1][1]);
    }
#pragma unroll
    for (int nt = 0; nt < 2; nt++) {
        int j = (ntb + nt) * 16 + fr;
        float sc = pS[j], sh = pH[j];
#pragma unroll
        for (int mt = 0; mt < 2; mt++)
#pragma unroll
            for (int r = 0; r < 4; r++) {
                int node = mt * 16 + fq * 4 + r;
                float v = fmaxf(acc[mt][nt][r] * sc + sh, 0.f);
                *(u16*)((char*)mid_s + node * 256 + ((2 * j) ^ ((node & 7) << 4))) = f2bf(v);
            }
    }
    __syncthreads();
    // ---- phase 2: (mid @ wb) + bb -> ReLU -> hout ----
#pragma unroll
    for (int nt = 0; nt < 2; nt++) {
        float b = pB[(ntb + nt) * 16 + fr];
        f32x4 bb4 = {b, b, b, b};
        acc[0][nt] = bb4; acc[1][nt] = bb4;
    }
#pragma unroll
    for (int kb = 0; kb < 4; kb++) {
        int koff = (kb * 64 + fq * 16) ^ xorv;
        bf16x8 a0 = *(const bf16x8*)((const char*)mid_s + fr * 256 + koff);
        bf16x8 a1 = *(const bf16x8*)((const char*)mid_s + (16 + fr) * 256 + koff);
        bf16x8 b0 = *(const bf16x8*)(WB + (ntb * 16 + fr) * 256 + koff);
        bf16x8 b1 = *(const bf16x8*)(WB + ((ntb + 1) * 16 + fr) * 256 + koff);
        acc[0][0] = MFMA16(a0, b0, acc[0][0]);
        acc[0][1] = MFMA16(a0, b1, acc[0][1]);
        acc[1][0] = MFMA16(a1, b0, acc[1][0]);
        acc[1][1] = MFMA16(a1, b1, acc[1][1]);
    }
#pragma unroll
    for (int nt = 0; nt < 2; nt++) {
        int j = (ntb + nt) * 16 + fr;
#pragma unroll
        for (int mt = 0; mt < 2; mt++)
#pragma unroll
            for (int r = 0; r < 4; r++) {
                int node = base + mt * 16 + fq * 4 + r;
                if (node < n) hout[node * DIM + j] = f2bf(fmaxf(acc[mt][nt][r], 0.f));
            }
    }
}

// ---- pool partials: 8 blocks per graph, each sums an eighth of its nodes ----
__global__ __launch_bounds__(256) void k_pool8(const int* __restrict__ batch,
                                               const u16* __restrict__ h1,
                                               const u16* __restrict__ h2,
                                               float* __restrict__ ppool) {
    int g = blockIdx.x >> 3, part = blockIdx.x & 7;
    int tid = threadIdx.x;
    int lo = 0, hi = N_NODES;
    while (lo < hi) { int m = (lo + hi) >> 1; if (batch[m] < g) lo = m + 1; else hi = m; }
    int start = lo;
    hi = N_NODES;
    while (lo < hi) { int m = (lo + hi) >> 1; if (batch[m] < g + 1) lo = m + 1; else hi = m; }
    int end = lo;
    int len = end - start;
    int qbeg = start + (len * part) / 8;
    int qend = start + (len * (part + 1)) / 8;

    int half = (tid >> 6) & 1;
    int ju = tid & 63;
    int par = tid >> 7;
    const u16* h = half ? h2 : h1;
    float a0 = 0.f, b0 = 0.f, a1 = 0.f, b1 = 0.f;
    float a2 = 0.f, b2 = 0.f, a3 = 0.f, b3 = 0.f;
    int i = qbeg + par;
    for (; i + 6 < qend; i += 8) {
        u32 v0 = *(const u32*)(h + (i    ) * DIM + ju * 2);
        u32 v1 = *(const u32*)(h + (i + 2) * DIM + ju * 2);
        u32 v2 = *(const u32*)(h + (i + 4) * DIM + ju * 2);
        u32 v3 = *(const u32*)(h + (i + 6) * DIM + ju * 2);
        a0 += bf2f((u16)v0); b0 += bf2f((u16)(v0 >> 16));
        a1 += bf2f((u16)v1); b1 += bf2f((u16)(v1 >> 16));
        a2 += bf2f((u16)v2); b2 += bf2f((u16)(v2 >> 16));
        a3 += bf2f((u16)v3); b3 += bf2f((u16)(v3 >> 16));
    }
    for (; i < qend; i += 2) {
        u32 v = *(const u32*)(h + i * DIM + ju * 2);
        a0 += bf2f((u16)v); b0 += bf2f((u16)(v >> 16));
    }
    float sa = (a0 + a1) + (a2 + a3);
    float sb = (b0 + b1) + (b2 + b3);
    __shared__ float2 red[2][128];
    red[par][half * 64 + ju] = make_float2(sa, sb);
    __syncthreads();
    if (tid < 128) {
        float2 r0 = red[0][tid], r1 = red[1][tid];
        ppool[blockIdx.x * 256 + tid * 2]     = r0.x + r1.x;
        ppool[blockIdx.x * 256 + tid * 2 + 1] = r0.y + r1.y;
    }
}

// ---- heads: reduce 8 partials -> relu(@wl1+bl1) -> @wl2+bl2 ------------------
__global__ __launch_bounds__(256) void k_heads(const float* __restrict__ ppool,
                                               const float* __restrict__ wl1,
                                               const float* __restrict__ bl1,
                                               const float* __restrict__ wl2,
                                               const float* __restrict__ bl2,
                                               float* __restrict__ out) {
    int g = blockIdx.x;
    int tid = threadIdx.x;
    __shared__ float pl[256];
    __shared__ float red[256];
    __shared__ float hgs[DIM];
    const float* p = ppool + g * 2048;
    float acc8 = 0.f;
#pragma unroll
    for (int k = 0; k < 8; k++) acc8 += p[k * 256 + tid];
    pl[tid] = acc8;
    __syncthreads();
    // head1: 2 threads per output j
    {
        int j = tid & 127, seg = tid >> 7;
        float acc = 0.f;
        const float* w = wl1 + (seg * 128) * DIM + j;
        const float* q = pl + seg * 128;
#pragma unroll 4
        for (int k = 0; k < 128; k++) acc = fmaf(q[k], w[k * DIM], acc);
        red[tid] = acc;
        __syncthreads();
        if (tid < 128) hgs[tid] = fmaxf(red[tid] + red[tid + 128] + bl1[tid], 0.f);
    }
    __syncthreads();
    if (tid < N_OUT) {
        float acc = bl2[tid];
#pragma unroll 4
        for (int k = 0; k < DIM; k++) acc = fmaf(hgs[k], wl2[k * N_OUT + tid], acc);
        out[g * N_OUT + tid] = acc;
    }
}

extern "C" void kernel_launch(void* const* d_in, const int* in_sizes, int n_in,
                              void* d_out, int out_size, void* d_ws, size_t ws_size,
                              hipStream_t stream) {
    const int* x_ids = (const int*)d_in[0];
    const int* edges = (const int*)d_in[1];
    const int* batch = (const int*)d_in[2];
    const float* emb = (const float*)d_in[3];
    const float *w11 = (const float*)d_in[4],  *b11 = (const float*)d_in[5];
    const float *g1  = (const float*)d_in[6],  *be1 = (const float*)d_in[7];
    const float *m1  = (const float*)d_in[8],  *v1  = (const float*)d_in[9];
    const float *w12 = (const float*)d_in[10], *b12 = (const float*)d_in[11];
    const float *w21 = (const float*)d_in[12], *b21 = (const float*)d_in[13];
    const float *g2  = (const float*)d_in[14], *be2 = (const float*)d_in[15];
    const float *m2  = (const float*)d_in[16], *v2  = (const float*)d_in[17];
    const float *w22 = (const float*)d_in[18], *b22 = (const float*)d_in[19];
    const float *wl1 = (const float*)d_in[20], *bl1 = (const float*)d_in[21];
    const float *wl2 = (const float*)d_in[22], *bl2 = (const float*)d_in[23];

    const int* src = edges;
    const int* dst = edges + N_EDGES;

    float* out_logits = (float*)d_out;                 // [500*10]
    float* xout = (float*)d_out + N_GR * N_OUT;        // [50000*128]

    char* ws = (char*)d_ws;
    float* ppool  = (float*)(ws + 12800000);           //  4,096,000 B (500*8*256 f32)
    u16*   h1     = (u16*)(ws + 25600000);             // 12,800,000 B
    u16*   h2     = (u16*)(ws + 38400000);             // 12,800,000 B
    // embbf/rank16 alias the h2 region: both dead before k_mlp<false> writes h2
    u16*   embbf  = (u16*)(ws + 38400000);             //    128,000 B
    u16*   rank16 = (u16*)(ws + 38528000);             //  1,600,000 B
    int*   bsum   = (int*)(ws + 51200000);
    int*   bpre   = (int*)(ws + 51204096);
    int*   deg    = (int*)(ws + 51968000);             //    200,000 B
    int*   rowptr = (int*)(ws + 52168000);             //    200,016 B
    u16*   wsz    = (u16*)(ws + 52368016);             //    131,072 B
    u32*   sid    = (u32*)(ws + 52568016);             //  3,200,000 B (ends 55.77 MB)

    u16* wsz1a = wsz;            u16* wsz1b = wsz + 16384;
    u16* wsz2a = wsz + 32768;    u16* wsz2b = wsz + 49152;

    // ---- prep (tables + deg zero), CSR build (gather overlapped) ----
    k_prep<<<449, 256, 0, stream>>>(w11, w12, w21, w22, emb, wsz, embbf, deg);
    k_hist_gather<<<GB_HIST + GB_GATH, 256, 0, stream>>>(dst, deg, rank16, x_ids, emb, xout);
    k_scan1<<<196, 256, 0, stream>>>(deg, bsum);
    k_scan2<<<1, 256, 0, stream>>>(bsum, bpre);
    k_scan3<<<196, 256, 0, stream>>>(deg, bpre, rowptr);
    k_fill<<<(N_EDGES + 255) / 256, 256, 0, stream>>>(src, dst, x_ids, rowptr, rank16, sid);

    // ---- layers (agg fused into low-LDS mlp) ----
    k_mlp<true><<<(N_NODES + 31) / 32, 256, 0, stream>>>(embbf, x_ids, sid, rowptr, wsz1a, b11, g1, be1, m1, v1, wsz1b, b12, h1, N_NODES);
    k_mlp<false><<<(N_NODES + 31) / 32, 256, 0, stream>>>(h1, nullptr, sid, rowptr, wsz2a, b21, g2, be2, m2, v2, wsz2b, b22, h2, N_NODES);

    // ---- readout ----
    k_pool8<<<N_GR * 8, 256, 0, stream>>>(batch, h1, h2, ppool);
    k_heads<<<N_GR, 256, 0, stream>>>(ppool, wl1, bl1, wl2, bl2, out_logits);
}